// Round 1
// baseline (486.095 us; speedup 1.0000x reference)
//
#include <hip/hip_runtime.h>

// Loss_Antonymy: per-row L2 distance -> tanh -> relu(1 +/- t) -> global sum.
// Round 6 design (contiguous-quad experiment):
//  - Wave handles 4 consecutive rows per load: lane i -> row (i>>4), slot (i&15).
//    Every global_load_dwordx4 covers one dense, aligned 1-KiB span (vs the
//    previous 8-lane/row scheme whose loads covered half-dense 2-KiB spans).
//  - 2-quad unroll: 4 vector loads (64 B) in flight per lane; 8 waves/SIMD
//    (__launch_bounds__(256,8)) -> 32 KB outstanding per SIMD, far above the
//    ~2.3 KB needed to cover HBM latency at the per-SIMD BW share.
//  - nt loads: read-once data, don't allocate in L2/L3 (kept from R4, won 20 us).
//  - No global atomics / no d_out memset: per-block partials in d_ws,
//    tiny finalize kernel reduces 2048 partials and writes d_out.

#define BLOCK 256
#define GRID  2048
#define NWAVES ((GRID * BLOCK) / 64)   // 8192 waves; 32 quads (128 rows) per wave

typedef float fx4 __attribute__((ext_vector_type(4)));

__device__ __forceinline__ fx4 ntload(const fx4* __restrict__ p) {
    return __builtin_nontemporal_load(p);
}

__device__ __forceinline__ float fast_err(float ss, int lab) {
    float d = sqrtf(ss);
    float e = __expf(2.0f * d);                               // v_exp_f32 based
    float t = 1.0f - 2.0f * __builtin_amdgcn_rcpf(e + 1.0f);  // tanh(d)
    float sgn = (lab == 2) ? -1.0f : 1.0f;
    return fmaxf(fmaf(sgn, t, 1.0f), 0.0f);
}

__device__ __forceinline__ float quad_partial(fx4 a, fx4 s) {
    float dx = a.x - s.x; float p = dx * dx;
    dx = a.y - s.y; p = fmaf(dx, dx, p);
    dx = a.z - s.z; p = fmaf(dx, dx, p);
    dx = a.w - s.w; p = fmaf(dx, dx, p);
    return p;
}

__global__ __launch_bounds__(BLOCK, 8) void loss_antonymy_kernel(
    const fx4* __restrict__ S2,   // float4 view of [N,64]
    const fx4* __restrict__ A1,
    const int* __restrict__ labels,
    float* __restrict__ partials,
    int n_rows)
{
    const int tid  = blockIdx.x * BLOCK + threadIdx.x;
    const int wid  = tid >> 6;              // global wave id, 0..NWAVES-1
    const int lane = threadIdx.x & 63;
    const int sub  = lane >> 4;             // row within quad, 0..3
    const int slot = lane & 15;             // float4 slot within row
    const int nquads = n_rows >> 2;         // 262144 quads of 4 rows

    float acc = 0.0f;

    // N = 1048576 -> nquads = 262144 = NWAVES * 32, exact (same divisibility
    // assumption as previous rounds).
    for (int q0 = wid; q0 < nquads; q0 += 2 * NWAVES) {
        const int qA = q0;
        const int qB = q0 + NWAVES;

        fx4 aA = ntload(A1 + (qA << 6) + lane);   // quad qA: dense 1-KiB span
        fx4 sA = ntload(S2 + (qA << 6) + lane);
        fx4 aB = ntload(A1 + (qB << 6) + lane);   // quad qB: dense 1-KiB span
        fx4 sB = ntload(S2 + (qB << 6) + lane);

        int labA = labels[(qA << 2) + sub];
        int labB = labels[(qB << 2) + sub];

        float ssA = quad_partial(aA, sA);
        float ssB = quad_partial(aB, sB);

        // 4-step xor butterfly within each 16-lane row group
        ssA += __shfl_xor(ssA, 1, 16);
        ssB += __shfl_xor(ssB, 1, 16);
        ssA += __shfl_xor(ssA, 2, 16);
        ssB += __shfl_xor(ssB, 2, 16);
        ssA += __shfl_xor(ssA, 4, 16);
        ssB += __shfl_xor(ssB, 4, 16);
        ssA += __shfl_xor(ssA, 8, 16);
        ssB += __shfl_xor(ssB, 8, 16);

        float errA = fast_err(ssA, labA);
        float errB = fast_err(ssB, labB);

        if (slot == 0) acc += errA + errB;
    }

    // wave-level reduction (64 lanes)
    for (int off = 32; off > 0; off >>= 1)
        acc += __shfl_down(acc, off, 64);

    __shared__ float wsum[BLOCK / 64];
    const int wave = threadIdx.x >> 6;
    if (lane == 0) wsum[wave] = acc;
    __syncthreads();

    if (wave == 0) {
        float v = (lane < (BLOCK / 64)) ? wsum[lane] : 0.0f;
        for (int off = 2; off > 0; off >>= 1)
            v += __shfl_down(v, off, 64);
        if (lane == 0) partials[blockIdx.x] = v;
    }
}

__global__ __launch_bounds__(256) void finalize_kernel(
    const float* __restrict__ partials, float* __restrict__ out)
{
    float acc = 0.0f;
    for (int i = threadIdx.x; i < GRID; i += 256)
        acc += partials[i];

    for (int off = 32; off > 0; off >>= 1)
        acc += __shfl_down(acc, off, 64);

    __shared__ float wsum[4];
    const int wave = threadIdx.x >> 6;
    const int lane = threadIdx.x & 63;
    if (lane == 0) wsum[wave] = acc;
    __syncthreads();

    if (threadIdx.x == 0)
        out[0] = wsum[0] + wsum[1] + wsum[2] + wsum[3];
}

extern "C" void kernel_launch(void* const* d_in, const int* in_sizes, int n_in,
                              void* d_out, int out_size, void* d_ws, size_t ws_size,
                              hipStream_t stream) {
    const fx4* S2     = (const fx4*)d_in[0];
    const fx4* A1     = (const fx4*)d_in[1];
    const int* labels = (const int*)d_in[2];
    float* partials   = (float*)d_ws;
    float* out        = (float*)d_out;

    const int n_rows = in_sizes[2];   // N = label count

    loss_antonymy_kernel<<<GRID, BLOCK, 0, stream>>>(S2, A1, labels, partials, n_rows);
    finalize_kernel<<<1, 256, 0, stream>>>(partials, out);
}